// Round 26
// baseline (398.403 us; speedup 1.0000x reference)
//
#include <hip/hip_runtime.h>
#include <math.h>

#define NIMG 50000
#define NKN  8192
#define BB   32
#define DD   512
#define CC   32
#define RR   16
#define KK   8
#define MMAX 384   // max KN class-bucket (mean 256, +8 sd)
#define SPLIT 4    // sims d-slices
#define SD4  (DD / 4 / SPLIT)   // 32 float4 per slice

typedef float f4v __attribute__((ext_vector_type(4)));

// ---------------------------------------------------------------- class lists
__global__ __launch_bounds__(256) void build_lists(const int* __restrict__ labels,
                                                   int n, int* __restrict__ cnt,
                                                   int* __restrict__ list, int stride) {
    int i = blockIdx.x * 256 + threadIdx.x;
    if (i < n) {
        int c = labels[i];
        int pos = atomicAdd(&cnt[c], 1);
        list[c * stride + pos] = i;
    }
}

// ---------------------------------------------------------------- sims v3 (r18/r20/r25 proven)
__global__ __launch_bounds__(256, 2) void sims_kernel(const float* __restrict__ Q,
                                                      const float* __restrict__ I,
                                                      float* __restrict__ SP) {
    int slice = blockIdx.y, tid = threadIdx.x;
    __shared__ float4 qs[BB][SD4];   // 16 KB
    for (int i = tid; i < BB * SD4; i += 256) {
        int b = i / SD4, d = i % SD4;
        qs[b][d] = ((const float4*)Q)[b * (DD / 4) + slice * SD4 + d];
    }
    __syncthreads();

    int n0 = blockIdx.x * 512 + tid;      // <= 49919 < NIMG
    int n1 = n0 + 256;
    bool v1ok = n1 < NIMG;
    int n1c = v1ok ? n1 : 0;

    float a0[BB], a1[BB];
#pragma unroll
    for (int b = 0; b < BB; b++) { a0[b] = 0.f; a1[b] = 0.f; }

    const float4* r0 = (const float4*)(I + (size_t)n0 * DD) + slice * SD4;
    const float4* r1 = (const float4*)(I + (size_t)n1c * DD) + slice * SD4;
    for (int d = 0; d < SD4; d++) {
        float4 x0 = r0[d], x1 = r1[d];
#pragma unroll
        for (int b = 0; b < BB; b++) {
            float4 q = qs[b][d];
            a0[b] += x0.x * q.x + x0.y * q.y + x0.z * q.z + x0.w * q.w;
            a1[b] += x1.x * q.x + x1.y * q.y + x1.z * q.z + x1.w * q.w;
        }
    }
    float* out = SP + (size_t)slice * BB * NIMG;
#pragma unroll
    for (int b = 0; b < BB; b++) {
        out[(size_t)b * NIMG + n0] = a0[b];
        if (v1ok) out[(size_t)b * NIMG + n1] = a1[b];
    }
}

// ---------------------------------------------------------------- topk + slice-combine + enhanced_images (fused)
// Candidate value = ((sp0+sp1)+sp2)+sp3 -- the exact combine_s sum order ->
// bitwise-identical selection to the r25 pipeline. After the 16 merge
// rounds, the same block gathers the image-fusion output (img_kernel's
// exact r-ascending order). Removes 2 dispatches + 50MB combine traffic.
__global__ __launch_bounds__(256) void topk_fused(const float* __restrict__ SP,
                                                  const int* __restrict__ cnt,
                                                  const int* __restrict__ list,
                                                  const float* __restrict__ Q,
                                                  const float* __restrict__ I,
                                                  int* __restrict__ t_idx,
                                                  float* __restrict__ t_w,
                                                  float* __restrict__ out) {
    int c = blockIdx.x, b = blockIdx.y, tid = threadIdx.x;
    int wave = tid >> 6, lane = tid & 63;
    __shared__ float wv_s[4];
    __shared__ int   wi_s[4];
    __shared__ float kv_s[RR];
    __shared__ int   ki_s[RR];
    __shared__ float w_s[RR];

    int m = cnt[c];
    const float* sp0 = SP + (size_t)b * NIMG;
    const float* sp1 = sp0 + (size_t)BB * NIMG;
    const float* sp2 = sp1 + (size_t)BB * NIMG;
    const float* sp3 = sp2 + (size_t)BB * NIMG;

    float cv0, cv1, cv2, cv3, cv4, cv5, cv6;
    int   ci0, ci1, ci2, ci3, ci4, ci5, ci6;
#define LOADC(t) { int j = tid + t * 256; \
        if (j < m) { int n = list[c * NIMG + j]; \
            cv##t = ((sp0[n] + sp1[n]) + sp2[n]) + sp3[n]; ci##t = n; } \
        else { cv##t = -1e30f; ci##t = 0x7fffffff; } }
    LOADC(0) LOADC(1) LOADC(2) LOADC(3) LOADC(4) LOADC(5) LOADC(6)
#undef LOADC

    unsigned used = 0;
#define CANDT(t) { if (!(used & (1u << t)) && \
                       (cv##t > mv || (cv##t == mv && ci##t < mj))) \
                   { mv = cv##t; mj = ci##t; mt = t; } }
#define RND(k) { \
        float mv = -1e30f; int mj = 0x7fffffff; int mt = -1; \
        CANDT(0) CANDT(1) CANDT(2) CANDT(3) CANDT(4) CANDT(5) CANDT(6) \
        int lmj = mj; \
        for (int off = 32; off > 0; off >>= 1) { \
            float ov = __shfl_xor(mv, off); \
            int   oj = __shfl_xor(mj, off); \
            if (ov > mv || (ov == mv && oj < mj)) { mv = ov; mj = oj; } \
        } \
        if (lane == 0) { wv_s[wave] = mv; wi_s[wave] = mj; } \
        __syncthreads(); \
        float gv = wv_s[0]; int gj = wi_s[0]; \
        if (wv_s[1] > gv || (wv_s[1] == gv && wi_s[1] < gj)) { gv = wv_s[1]; gj = wi_s[1]; } \
        if (wv_s[2] > gv || (wv_s[2] == gv && wi_s[2] < gj)) { gv = wv_s[2]; gj = wi_s[2]; } \
        if (wv_s[3] > gv || (wv_s[3] == gv && wi_s[3] < gj)) { gv = wv_s[3]; gj = wi_s[3]; } \
        if (mt >= 0 && lmj == gj && lmj != 0x7fffffff) used |= (1u << mt); \
        if (tid == 0) { kv_s[k] = gv; ki_s[k] = gj; } \
        __syncthreads(); }

    RND(0)  RND(1)  RND(2)  RND(3)  RND(4)  RND(5)  RND(6)  RND(7)
    RND(8)  RND(9)  RND(10) RND(11) RND(12) RND(13) RND(14) RND(15)
#undef RND
#undef CANDT

    if (tid == 0) {
        float mx = kv_s[0], s = 0.f, e[RR];
#pragma unroll
        for (int k = 0; k < RR; k++) { e[k] = expf(kv_s[k] - mx); s += e[k]; }
        float inv = 1.f / s;
        size_t o = ((size_t)(b * CC) + c) * RR;
#pragma unroll
        for (int k = 0; k < RR; k++) {
            float wk = e[k] * inv;
            t_w[o + k] = wk; w_s[k] = wk; t_idx[o + k] = ki_s[k];
        }
    }
    __syncthreads();

    // ---- enhanced_images gather (img_kernel's exact order)
    for (int d = tid; d < DD; d += 256) {
        float acc = 0.f;
#pragma unroll
        for (int r = 0; r < RR; r++) acc += w_s[r] * I[(size_t)ki_s[r] * DD + d];
        out[((size_t)(b * CC) + c) * DD + d] = 0.5f * (Q[b * DD + d] + acc);
    }
}

// ---------------------------------------------------------------- gather-transpose
__global__ __launch_bounds__(256) void transpose_kn(const float* __restrict__ KN,
                                                    const int* __restrict__ kcnt,
                                                    const int* __restrict__ klist,
                                                    float4* __restrict__ KT4) {
    int c = blockIdx.x;
    int w = threadIdx.x >> 6, lane = threadIdx.x & 63;
    int j = blockIdx.y * 4 + w;
    int m = kcnt[c]; if (m > MMAX) m = MMAX;
    int row = klist[c * NKN + (j < m ? j : 0)];
    const float4* src = (const float4*)(KN + (size_t)row * DD);
    float4* dst = KT4 + (size_t)c * (DD / 4) * MMAX;
    float4 v0 = src[lane], v1 = src[lane + 64];
    dst[(size_t)lane * MMAX + j]        = v0;
    dst[(size_t)(lane + 64) * MMAX + j] = v1;
}

// ---------------------------------------------------------------- knowledge v13 (r20/r23/r25 proven, 140us)
__global__ __launch_bounds__(256, 4) void knowledge_kernel(const float* __restrict__ Q,
                                                           const float* __restrict__ I,
                                                           const float* __restrict__ KN,
                                                           const float4* __restrict__ KT4,
                                                           const int* __restrict__ kcnt,
                                                           const int* __restrict__ klist,
                                                           const int* __restrict__ t_idx,
                                                           const float* __restrict__ t_w,
                                                           float* __restrict__ outk) {
    int c = blockIdx.x, b = blockIdx.y;
    int tid = threadIdx.x, wave = tid >> 6, lane = tid & 63;
    int rbase = wave * 4;

    __shared__ float  s_iw[RR];
    __shared__ int    s_ii[RR];
    __shared__ float  wgt[RR][KK];
    __shared__ int    kidx[RR][KK];

    if (tid < RR) {
        size_t o = ((size_t)(b * CC) + c) * RR;
        s_iw[tid] = t_w[o + tid]; s_ii[tid] = t_idx[o + tid];
    }
    __syncthreads();

    // wave-uniform image-row pointers (scalar pipe)
    int i0 = __builtin_amdgcn_readfirstlane(s_ii[rbase + 0]);
    int i1 = __builtin_amdgcn_readfirstlane(s_ii[rbase + 1]);
    int i2 = __builtin_amdgcn_readfirstlane(s_ii[rbase + 2]);
    int i3 = __builtin_amdgcn_readfirstlane(s_ii[rbase + 3]);
    const float4* U0 = (const float4*)(I + (size_t)i0 * DD);
    const float4* U1 = (const float4*)(I + (size_t)i1 * DD);
    const float4* U2 = (const float4*)(I + (size_t)i2 * DD);
    const float4* U3 = (const float4*)(I + (size_t)i3 * DD);

    int m = kcnt[c]; if (m > MMAX) m = MMAX;
    int ng = (m + 63) >> 6;
    const float4* KTc = KT4 + (size_t)c * (DD / 4) * MMAX;

    f4v A0 = 0.f, A1 = 0.f, A2 = 0.f, A3 = 0.f, A4 = 0.f, A5 = 0.f;

#define LG(g) float4 kk##g = p[g * 64];
#define FG(g, rr) A##g[rr] = fmaf(kk##g.x, u.x, fmaf(kk##g.y, u.y, \
                   fmaf(kk##g.z, u.z, fmaf(kk##g.w, u.w, A##g[rr]))));
#define RRBLK(rr, FMAS) { float4 u = U##rr[d4]; FMAS }
#define SCORE(LOADS, F0, F1, F2, F3) \
        for (int d4 = 0; d4 < DD / 4; d4++) { \
            const float4* p = KTc + (size_t)d4 * MMAX + lane; \
            LOADS \
            RRBLK(0, F0) RRBLK(1, F1) RRBLK(2, F2) RRBLK(3, F3) }

    if (ng <= 4) {
        SCORE(LG(0) LG(1) LG(2) LG(3),
              FG(0,0) FG(1,0) FG(2,0) FG(3,0),
              FG(0,1) FG(1,1) FG(2,1) FG(3,1),
              FG(0,2) FG(1,2) FG(2,2) FG(3,2),
              FG(0,3) FG(1,3) FG(2,3) FG(3,3))
    } else if (ng == 5) {
        SCORE(LG(0) LG(1) LG(2) LG(3) LG(4),
              FG(0,0) FG(1,0) FG(2,0) FG(3,0) FG(4,0),
              FG(0,1) FG(1,1) FG(2,1) FG(3,1) FG(4,1),
              FG(0,2) FG(1,2) FG(2,2) FG(3,2) FG(4,2),
              FG(0,3) FG(1,3) FG(2,3) FG(3,3) FG(4,3))
    } else {
        SCORE(LG(0) LG(1) LG(2) LG(3) LG(4) LG(5),
              FG(0,0) FG(1,0) FG(2,0) FG(3,0) FG(4,0) FG(5,0),
              FG(0,1) FG(1,1) FG(2,1) FG(3,1) FG(4,1) FG(5,1),
              FG(0,2) FG(1,2) FG(2,2) FG(3,2) FG(4,2) FG(5,2),
              FG(0,3) FG(1,3) FG(2,3) FG(3,3) FG(4,3) FG(5,3))
    }
#undef SCORE
#undef RRBLK
#undef FG
#undef LG

#define CAND(t) { if (!(used & (1u << t)) && \
                      (lv##t > mv || (lv##t == mv && (t * 64 + lane) < mj))) \
                  { mv = lv##t; mj = t * 64 + lane; mt = t; } }

#define ROUND(k) { \
        float mv = -1e30f; int mj = 0x7fffffff; int mt = -1; \
        CAND(0) CAND(1) CAND(2) CAND(3) CAND(4) CAND(5) \
        int cj = mj; \
        for (int off = 32; off > 0; off >>= 1) { \
            float ov = __shfl_xor(mv, off); \
            int   oj = __shfl_xor(mj, off); \
            if (ov > mv || (ov == mv && oj < mj)) { mv = ov; mj = oj; } \
        } \
        if (cj == mj && mt >= 0) used |= (1u << mt); \
        if (lane == k) myj = mj; \
        kv##k = mv; }

#define TOPK_RR(rr) { \
        int r = rbase + rr; \
        float lv0 = (0 * 64 + lane < m) ? A0[rr] : -1e30f; \
        float lv1 = (1 * 64 + lane < m) ? A1[rr] : -1e30f; \
        float lv2 = (2 * 64 + lane < m) ? A2[rr] : -1e30f; \
        float lv3 = (3 * 64 + lane < m) ? A3[rr] : -1e30f; \
        float lv4 = (4 * 64 + lane < m) ? A4[rr] : -1e30f; \
        float lv5 = (5 * 64 + lane < m) ? A5[rr] : -1e30f; \
        unsigned used = 0; int myj = 0; \
        float kv0, kv1, kv2, kv3, kv4, kv5, kv6, kv7; \
        ROUND(0) ROUND(1) ROUND(2) ROUND(3) \
        ROUND(4) ROUND(5) ROUND(6) ROUND(7) \
        if (lane < KK) kidx[r][lane] = klist[c * NKN + myj]; \
        if (lane == 0) { \
            float e0 = 1.f; \
            float e1 = expf(kv1 - kv0), e2 = expf(kv2 - kv0), e3 = expf(kv3 - kv0); \
            float e4 = expf(kv4 - kv0), e5 = expf(kv5 - kv0), e6 = expf(kv6 - kv0); \
            float e7 = expf(kv7 - kv0); \
            float s = e0 + e1 + e2 + e3 + e4 + e5 + e6 + e7; \
            float wr = s_iw[r] / s; \
            wgt[r][0] = e0 * wr; wgt[r][1] = e1 * wr; wgt[r][2] = e2 * wr; \
            wgt[r][3] = e3 * wr; wgt[r][4] = e4 * wr; wgt[r][5] = e5 * wr; \
            wgt[r][6] = e6 * wr; wgt[r][7] = e7 * wr; \
        } }

    TOPK_RR(0) TOPK_RR(1) TOPK_RR(2) TOPK_RR(3)
#undef TOPK_RR
#undef ROUND
#undef CAND

    __syncthreads();

    float acc0 = 0.f, acc1 = 0.f;
#pragma unroll 8
    for (int p = 0; p < RR * KK; p++) {
        int r = p >> 3, k = p & 7;
        float w = wgt[r][k];
        const float* kp = KN + (size_t)kidx[r][k] * DD;
        acc0 += w * kp[tid];
        acc1 += w * kp[tid + 256];
    }
    size_t o = ((size_t)(b * CC) + c) * DD;
    outk[o + tid]       = 0.5f * (Q[b * DD + tid] + acc0);
    outk[o + tid + 256] = 0.5f * (Q[b * DD + tid + 256] + acc1);
}

// ---------------------------------------------------------------- launch
extern "C" void kernel_launch(void* const* d_in, const int* in_sizes, int n_in,
                              void* d_out, int out_size, void* d_ws, size_t ws_size,
                              hipStream_t stream) {
    const float* Q  = (const float*)d_in[0];
    const float* I  = (const float*)d_in[1];
    const float* KN = (const float*)d_in[2];
    const int* ilab = (const int*)d_in[3];
    const int* klab = (const int*)d_in[4];

    char* ws = (char*)d_ws;
    float* SP       = (float*)ws;  ws += (size_t)SPLIT * BB * NIMG * 4;  // 25.6 MB
    int*   img_list = (int*)ws;    ws += (size_t)CC * NIMG * 4;
    int*   kn_list  = (int*)ws;    ws += (size_t)CC * NKN * 4;
    int*   t_idx    = (int*)ws;    ws += (size_t)BB * CC * RR * 4;
    float* t_w      = (float*)ws;  ws += (size_t)BB * CC * RR * 4;
    int*   img_cnt  = (int*)ws;    ws += CC * 4;
    int*   kn_cnt   = (int*)ws;    ws += CC * 4;
    ws = (char*)(((size_t)ws + 255) & ~(size_t)255);   // align 256B
    float4* KT4     = (float4*)ws; ws += (size_t)CC * (DD / 4) * MMAX * 16;  // 25.2 MB

    float* out_img = (float*)d_out;
    float* out_kn  = out_img + (size_t)BB * CC * DD;

    hipMemsetAsync(img_cnt, 0, 2 * CC * 4, stream);  // img_cnt + kn_cnt contiguous

    build_lists<<<(NIMG + 255) / 256, 256, 0, stream>>>(ilab, NIMG, img_cnt, img_list, NIMG);
    build_lists<<<(NKN  + 255) / 256, 256, 0, stream>>>(klab, NKN,  kn_cnt,  kn_list,  NKN);
    transpose_kn<<<dim3(CC, MMAX / 4), 256, 0, stream>>>(KN, kn_cnt, kn_list, KT4);
    sims_kernel<<<dim3((NIMG + 511) / 512, SPLIT), 256, 0, stream>>>(Q, I, SP);
    topk_fused<<<dim3(CC, BB), 256, 0, stream>>>(SP, img_cnt, img_list, Q, I, t_idx, t_w, out_img);
    knowledge_kernel<<<dim3(CC, BB), 256, 0, stream>>>(Q, I, KN, KT4, kn_cnt, kn_list, t_idx, t_w, out_kn);
}

// Round 27
// 363.827 us; speedup vs baseline: 1.0950x; 1.0950x over previous
//
#include <hip/hip_runtime.h>
#include <math.h>

#define NIMG 50000
#define NKN  8192
#define BB   32
#define DD   512
#define CC   32
#define RR   16
#define KK   8
#define MMAX 384   // max KN class-bucket (mean 256, +8 sd)
#define SPLIT 4    // sims d-slices
#define SD4  (DD / 4 / SPLIT)   // 32 float4 per slice

typedef float f4v __attribute__((ext_vector_type(4)));

// ---------------------------------------------------------------- class lists
__global__ __launch_bounds__(256) void build_lists(const int* __restrict__ labels,
                                                   int n, int* __restrict__ cnt,
                                                   int* __restrict__ list, int stride) {
    int i = blockIdx.x * 256 + threadIdx.x;
    if (i < n) {
        int c = labels[i];
        int pos = atomicAdd(&cnt[c], 1);
        list[c * stride + pos] = i;
    }
}

// ---------------------------------------------------------------- sims v3 (r18/r20/r25 proven best)
__global__ __launch_bounds__(256, 2) void sims_kernel(const float* __restrict__ Q,
                                                      const float* __restrict__ I,
                                                      float* __restrict__ SP) {
    int slice = blockIdx.y, tid = threadIdx.x;
    __shared__ float4 qs[BB][SD4];   // 16 KB
    for (int i = tid; i < BB * SD4; i += 256) {
        int b = i / SD4, d = i % SD4;
        qs[b][d] = ((const float4*)Q)[b * (DD / 4) + slice * SD4 + d];
    }
    __syncthreads();

    int n0 = blockIdx.x * 512 + tid;      // <= 49919 < NIMG
    int n1 = n0 + 256;
    bool v1ok = n1 < NIMG;
    int n1c = v1ok ? n1 : 0;

    float a0[BB], a1[BB];
#pragma unroll
    for (int b = 0; b < BB; b++) { a0[b] = 0.f; a1[b] = 0.f; }

    const float4* r0 = (const float4*)(I + (size_t)n0 * DD) + slice * SD4;
    const float4* r1 = (const float4*)(I + (size_t)n1c * DD) + slice * SD4;
    for (int d = 0; d < SD4; d++) {
        float4 x0 = r0[d], x1 = r1[d];
#pragma unroll
        for (int b = 0; b < BB; b++) {
            float4 q = qs[b][d];
            a0[b] += x0.x * q.x + x0.y * q.y + x0.z * q.z + x0.w * q.w;
            a1[b] += x1.x * q.x + x1.y * q.y + x1.z * q.z + x1.w * q.w;
        }
    }
    float* out = SP + (size_t)slice * BB * NIMG;
#pragma unroll
    for (int b = 0; b < BB; b++) {
        out[(size_t)b * NIMG + n0] = a0[b];
        if (v1ok) out[(size_t)b * NIMG + n1] = a1[b];
    }
}

// ---------------------------------------------------------------- combine 4 slices (fixed order)
__global__ __launch_bounds__(256) void combine_s(float4* __restrict__ SP) {
    int i = blockIdx.x * 256 + threadIdx.x;
    const int n4 = BB * NIMG / 4;        // 400000
    if (i >= n4) return;
    float4 s0 = SP[i], s1 = SP[i + n4], s2 = SP[i + 2 * n4], s3 = SP[i + 3 * n4];
    float4 r;
    r.x = ((s0.x + s1.x) + s2.x) + s3.x;
    r.y = ((s0.y + s1.y) + s2.y) + s3.y;
    r.z = ((s0.z + s1.z) + s2.z) + s3.z;
    r.w = ((s0.w + s1.w) + s2.w) + s3.w;
    SP[i] = r;
}

// ---------------------------------------------------------------- topk_img v2
__global__ __launch_bounds__(256) void topk_img(const float* __restrict__ S,
                                                const int* __restrict__ cnt,
                                                const int* __restrict__ list,
                                                int* __restrict__ t_idx,
                                                float* __restrict__ t_w) {
    int c = blockIdx.x, b = blockIdx.y, tid = threadIdx.x;
    int wave = tid >> 6, lane = tid & 63;
    __shared__ float wv_s[4];
    __shared__ int   wi_s[4];
    __shared__ float kv_s[RR];
    __shared__ int   ki_s[RR];

    int m = cnt[c];
    const float* Sb = S + (size_t)b * NIMG;

    float cv0, cv1, cv2, cv3, cv4, cv5, cv6;
    int   ci0, ci1, ci2, ci3, ci4, ci5, ci6;
#define LOADC(t) { int j = tid + t * 256; \
        if (j < m) { int n = list[c * NIMG + j]; cv##t = Sb[n]; ci##t = n; } \
        else { cv##t = -1e30f; ci##t = 0x7fffffff; } }
    LOADC(0) LOADC(1) LOADC(2) LOADC(3) LOADC(4) LOADC(5) LOADC(6)
#undef LOADC

    unsigned used = 0;
#define CANDT(t) { if (!(used & (1u << t)) && \
                       (cv##t > mv || (cv##t == mv && ci##t < mj))) \
                   { mv = cv##t; mj = ci##t; mt = t; } }
#define RND(k) { \
        float mv = -1e30f; int mj = 0x7fffffff; int mt = -1; \
        CANDT(0) CANDT(1) CANDT(2) CANDT(3) CANDT(4) CANDT(5) CANDT(6) \
        int lmj = mj; \
        for (int off = 32; off > 0; off >>= 1) { \
            float ov = __shfl_xor(mv, off); \
            int   oj = __shfl_xor(mj, off); \
            if (ov > mv || (ov == mv && oj < mj)) { mv = ov; mj = oj; } \
        } \
        if (lane == 0) { wv_s[wave] = mv; wi_s[wave] = mj; } \
        __syncthreads(); \
        float gv = wv_s[0]; int gj = wi_s[0]; \
        if (wv_s[1] > gv || (wv_s[1] == gv && wi_s[1] < gj)) { gv = wv_s[1]; gj = wi_s[1]; } \
        if (wv_s[2] > gv || (wv_s[2] == gv && wi_s[2] < gj)) { gv = wv_s[2]; gj = wi_s[2]; } \
        if (wv_s[3] > gv || (wv_s[3] == gv && wi_s[3] < gj)) { gv = wv_s[3]; gj = wi_s[3]; } \
        if (mt >= 0 && lmj == gj && lmj != 0x7fffffff) used |= (1u << mt); \
        if (tid == 0) { kv_s[k] = gv; ki_s[k] = gj; } \
        __syncthreads(); }

    RND(0)  RND(1)  RND(2)  RND(3)  RND(4)  RND(5)  RND(6)  RND(7)
    RND(8)  RND(9)  RND(10) RND(11) RND(12) RND(13) RND(14) RND(15)
#undef RND
#undef CANDT

    if (tid == 0) {
        float mx = kv_s[0], s = 0.f, e[RR];
#pragma unroll
        for (int k = 0; k < RR; k++) { e[k] = expf(kv_s[k] - mx); s += e[k]; }
        float inv = 1.f / s;
        size_t o = ((size_t)(b * CC) + c) * RR;
#pragma unroll
        for (int k = 0; k < RR; k++) { t_w[o + k] = e[k] * inv; t_idx[o + k] = ki_s[k]; }
    }
}

// ---------------------------------------------------------------- enhanced_images
__global__ __launch_bounds__(256) void img_kernel(const float* __restrict__ Q,
                                                  const float* __restrict__ I,
                                                  const int* __restrict__ t_idx,
                                                  const float* __restrict__ t_w,
                                                  float* __restrict__ out) {
    int c = blockIdx.x, b = blockIdx.y, tid = threadIdx.x;
    __shared__ float w[RR];
    __shared__ int   id[RR];
    if (tid < RR) {
        size_t o = ((size_t)(b * CC) + c) * RR;
        w[tid] = t_w[o + tid]; id[tid] = t_idx[o + tid];
    }
    __syncthreads();
    for (int d = tid; d < DD; d += 256) {
        float acc = 0.f;
#pragma unroll
        for (int r = 0; r < RR; r++) acc += w[r] * I[(size_t)id[r] * DD + d];
        out[((size_t)(b * CC) + c) * DD + d] = 0.5f * (Q[b * DD + d] + acc);
    }
}

// ---------------------------------------------------------------- gather-transpose
__global__ __launch_bounds__(256) void transpose_kn(const float* __restrict__ KN,
                                                    const int* __restrict__ kcnt,
                                                    const int* __restrict__ klist,
                                                    float4* __restrict__ KT4) {
    int c = blockIdx.x;
    int w = threadIdx.x >> 6, lane = threadIdx.x & 63;
    int j = blockIdx.y * 4 + w;
    int m = kcnt[c]; if (m > MMAX) m = MMAX;
    int row = klist[c * NKN + (j < m ? j : 0)];
    const float4* src = (const float4*)(KN + (size_t)row * DD);
    float4* dst = KT4 + (size_t)c * (DD / 4) * MMAX;
    float4 v0 = src[lane], v1 = src[lane + 64];
    dst[(size_t)lane * MMAX + j]        = v0;
    dst[(size_t)(lane + 64) * MMAX + j] = v1;
}

// ---------------------------------------------------------------- knowledge v13 (r20/r23/r25 proven, 140us)
__global__ __launch_bounds__(256, 4) void knowledge_kernel(const float* __restrict__ Q,
                                                           const float* __restrict__ I,
                                                           const float* __restrict__ KN,
                                                           const float4* __restrict__ KT4,
                                                           const int* __restrict__ kcnt,
                                                           const int* __restrict__ klist,
                                                           const int* __restrict__ t_idx,
                                                           const float* __restrict__ t_w,
                                                           float* __restrict__ outk) {
    int c = blockIdx.x, b = blockIdx.y;
    int tid = threadIdx.x, wave = tid >> 6, lane = tid & 63;
    int rbase = wave * 4;

    __shared__ float  s_iw[RR];
    __shared__ int    s_ii[RR];
    __shared__ float  wgt[RR][KK];
    __shared__ int    kidx[RR][KK];

    if (tid < RR) {
        size_t o = ((size_t)(b * CC) + c) * RR;
        s_iw[tid] = t_w[o + tid]; s_ii[tid] = t_idx[o + tid];
    }
    __syncthreads();

    // wave-uniform image-row pointers (scalar pipe)
    int i0 = __builtin_amdgcn_readfirstlane(s_ii[rbase + 0]);
    int i1 = __builtin_amdgcn_readfirstlane(s_ii[rbase + 1]);
    int i2 = __builtin_amdgcn_readfirstlane(s_ii[rbase + 2]);
    int i3 = __builtin_amdgcn_readfirstlane(s_ii[rbase + 3]);
    const float4* U0 = (const float4*)(I + (size_t)i0 * DD);
    const float4* U1 = (const float4*)(I + (size_t)i1 * DD);
    const float4* U2 = (const float4*)(I + (size_t)i2 * DD);
    const float4* U3 = (const float4*)(I + (size_t)i3 * DD);

    int m = kcnt[c]; if (m > MMAX) m = MMAX;
    int ng = (m + 63) >> 6;
    const float4* KTc = KT4 + (size_t)c * (DD / 4) * MMAX;

    f4v A0 = 0.f, A1 = 0.f, A2 = 0.f, A3 = 0.f, A4 = 0.f, A5 = 0.f;

#define LG(g) float4 kk##g = p[g * 64];
#define FG(g, rr) A##g[rr] = fmaf(kk##g.x, u.x, fmaf(kk##g.y, u.y, \
                   fmaf(kk##g.z, u.z, fmaf(kk##g.w, u.w, A##g[rr]))));
#define RRBLK(rr, FMAS) { float4 u = U##rr[d4]; FMAS }
#define SCORE(LOADS, F0, F1, F2, F3) \
        for (int d4 = 0; d4 < DD / 4; d4++) { \
            const float4* p = KTc + (size_t)d4 * MMAX + lane; \
            LOADS \
            RRBLK(0, F0) RRBLK(1, F1) RRBLK(2, F2) RRBLK(3, F3) }

    if (ng <= 4) {
        SCORE(LG(0) LG(1) LG(2) LG(3),
              FG(0,0) FG(1,0) FG(2,0) FG(3,0),
              FG(0,1) FG(1,1) FG(2,1) FG(3,1),
              FG(0,2) FG(1,2) FG(2,2) FG(3,2),
              FG(0,3) FG(1,3) FG(2,3) FG(3,3))
    } else if (ng == 5) {
        SCORE(LG(0) LG(1) LG(2) LG(3) LG(4),
              FG(0,0) FG(1,0) FG(2,0) FG(3,0) FG(4,0),
              FG(0,1) FG(1,1) FG(2,1) FG(3,1) FG(4,1),
              FG(0,2) FG(1,2) FG(2,2) FG(3,2) FG(4,2),
              FG(0,3) FG(1,3) FG(2,3) FG(3,3) FG(4,3))
    } else {
        SCORE(LG(0) LG(1) LG(2) LG(3) LG(4) LG(5),
              FG(0,0) FG(1,0) FG(2,0) FG(3,0) FG(4,0) FG(5,0),
              FG(0,1) FG(1,1) FG(2,1) FG(3,1) FG(4,1) FG(5,1),
              FG(0,2) FG(1,2) FG(2,2) FG(3,2) FG(4,2) FG(5,2),
              FG(0,3) FG(1,3) FG(2,3) FG(3,3) FG(4,3) FG(5,3))
    }
#undef SCORE
#undef RRBLK
#undef FG
#undef LG

#define CAND(t) { if (!(used & (1u << t)) && \
                      (lv##t > mv || (lv##t == mv && (t * 64 + lane) < mj))) \
                  { mv = lv##t; mj = t * 64 + lane; mt = t; } }

#define ROUND(k) { \
        float mv = -1e30f; int mj = 0x7fffffff; int mt = -1; \
        CAND(0) CAND(1) CAND(2) CAND(3) CAND(4) CAND(5) \
        int cj = mj; \
        for (int off = 32; off > 0; off >>= 1) { \
            float ov = __shfl_xor(mv, off); \
            int   oj = __shfl_xor(mj, off); \
            if (ov > mv || (ov == mv && oj < mj)) { mv = ov; mj = oj; } \
        } \
        if (cj == mj && mt >= 0) used |= (1u << mt); \
        if (lane == k) myj = mj; \
        kv##k = mv; }

#define TOPK_RR(rr) { \
        int r = rbase + rr; \
        float lv0 = (0 * 64 + lane < m) ? A0[rr] : -1e30f; \
        float lv1 = (1 * 64 + lane < m) ? A1[rr] : -1e30f; \
        float lv2 = (2 * 64 + lane < m) ? A2[rr] : -1e30f; \
        float lv3 = (3 * 64 + lane < m) ? A3[rr] : -1e30f; \
        float lv4 = (4 * 64 + lane < m) ? A4[rr] : -1e30f; \
        float lv5 = (5 * 64 + lane < m) ? A5[rr] : -1e30f; \
        unsigned used = 0; int myj = 0; \
        float kv0, kv1, kv2, kv3, kv4, kv5, kv6, kv7; \
        ROUND(0) ROUND(1) ROUND(2) ROUND(3) \
        ROUND(4) ROUND(5) ROUND(6) ROUND(7) \
        if (lane < KK) kidx[r][lane] = klist[c * NKN + myj]; \
        if (lane == 0) { \
            float e0 = 1.f; \
            float e1 = expf(kv1 - kv0), e2 = expf(kv2 - kv0), e3 = expf(kv3 - kv0); \
            float e4 = expf(kv4 - kv0), e5 = expf(kv5 - kv0), e6 = expf(kv6 - kv0); \
            float e7 = expf(kv7 - kv0); \
            float s = e0 + e1 + e2 + e3 + e4 + e5 + e6 + e7; \
            float wr = s_iw[r] / s; \
            wgt[r][0] = e0 * wr; wgt[r][1] = e1 * wr; wgt[r][2] = e2 * wr; \
            wgt[r][3] = e3 * wr; wgt[r][4] = e4 * wr; wgt[r][5] = e5 * wr; \
            wgt[r][6] = e6 * wr; wgt[r][7] = e7 * wr; \
        } }

    TOPK_RR(0) TOPK_RR(1) TOPK_RR(2) TOPK_RR(3)
#undef TOPK_RR
#undef ROUND
#undef CAND

    __syncthreads();

    float acc0 = 0.f, acc1 = 0.f;
#pragma unroll 8
    for (int p = 0; p < RR * KK; p++) {
        int r = p >> 3, k = p & 7;
        float w = wgt[r][k];
        const float* kp = KN + (size_t)kidx[r][k] * DD;
        acc0 += w * kp[tid];
        acc1 += w * kp[tid + 256];
    }
    size_t o = ((size_t)(b * CC) + c) * DD;
    outk[o + tid]       = 0.5f * (Q[b * DD + tid] + acc0);
    outk[o + tid + 256] = 0.5f * (Q[b * DD + tid + 256] + acc1);
}

// ---------------------------------------------------------------- launch
extern "C" void kernel_launch(void* const* d_in, const int* in_sizes, int n_in,
                              void* d_out, int out_size, void* d_ws, size_t ws_size,
                              hipStream_t stream) {
    const float* Q  = (const float*)d_in[0];
    const float* I  = (const float*)d_in[1];
    const float* KN = (const float*)d_in[2];
    const int* ilab = (const int*)d_in[3];
    const int* klab = (const int*)d_in[4];

    char* ws = (char*)d_ws;
    float* SP       = (float*)ws;  ws += (size_t)SPLIT * BB * NIMG * 4;  // 25.6 MB
    int*   img_list = (int*)ws;    ws += (size_t)CC * NIMG * 4;
    int*   kn_list  = (int*)ws;    ws += (size_t)CC * NKN * 4;
    int*   t_idx    = (int*)ws;    ws += (size_t)BB * CC * RR * 4;
    float* t_w      = (float*)ws;  ws += (size_t)BB * CC * RR * 4;
    int*   img_cnt  = (int*)ws;    ws += CC * 4;
    int*   kn_cnt   = (int*)ws;    ws += CC * 4;
    ws = (char*)(((size_t)ws + 255) & ~(size_t)255);   // align 256B
    float4* KT4     = (float4*)ws; ws += (size_t)CC * (DD / 4) * MMAX * 16;  // 25.2 MB

    float* out_img = (float*)d_out;
    float* out_kn  = out_img + (size_t)BB * CC * DD;

    hipMemsetAsync(img_cnt, 0, 2 * CC * 4, stream);  // img_cnt + kn_cnt contiguous

    build_lists<<<(NIMG + 255) / 256, 256, 0, stream>>>(ilab, NIMG, img_cnt, img_list, NIMG);
    build_lists<<<(NKN  + 255) / 256, 256, 0, stream>>>(klab, NKN,  kn_cnt,  kn_list,  NKN);
    transpose_kn<<<dim3(CC, MMAX / 4), 256, 0, stream>>>(KN, kn_cnt, kn_list, KT4);
    sims_kernel<<<dim3((NIMG + 511) / 512, SPLIT), 256, 0, stream>>>(Q, I, SP);
    combine_s<<<(BB * NIMG / 4 + 255) / 256, 256, 0, stream>>>((float4*)SP);
    topk_img<<<dim3(CC, BB), 256, 0, stream>>>(SP, img_cnt, img_list, t_idx, t_w);
    img_kernel<<<dim3(CC, BB), 256, 0, stream>>>(Q, I, t_idx, t_w, (float*)d_out);
    knowledge_kernel<<<dim3(CC, BB), 256, 0, stream>>>(Q, I, KN, KT4, kn_cnt, kn_list, t_idx, t_w, out_kn);
}